// Round 6
// baseline (86.380 us; speedup 1.0000x reference)
//
#include <hip/hip_runtime.h>
#include <math.h>

// Problem constants (x: (5,1,256,64,64) f32)
constexpr int NIMG = 5;
constexpr int CCH  = 256;   // channels (both c and d)
constexpr int HWP  = 4096;  // H*W
constexpr int PT   = CCH * HWP;  // elems per image = 1048576

// Tiling: 64 d x 32 p per block, K-step 16, double-buffered, n-loop in block.
// Micro-tile per thread: 4 d-rows x 2 p x 5 images (dual acc) = 80 acc regs.
// LDS intensity: (5*8 + 2*16) B per 84 VALU-op -> ~0.64 B/FLOP (was 1.2).
constexpr int BD = 64;
constexpr int BP = 32;
constexpr int BK = 16;
constexpr int NSTEP = CCH / BK;   // 16

// Async global->LDS, 16B/lane. LDS dest is wave-uniform base; HW adds lane*16.
__device__ __forceinline__ void gload16(const float* g, float* l) {
    __builtin_amdgcn_global_load_lds(
        (const __attribute__((address_space(1))) unsigned int*)g,
        (__attribute__((address_space(3))) unsigned int*)l, 16, 0, 0);
}

// -----------------------------------------------------------------------------
// Fully fused: per block (d0,p0), all 5 images; 2-phase double-buffered K-loop,
// counted vmcnt (loads stay in flight across barriers). Math chain identical
// to passing versions: acc_s += (w1+w2)*x per cc, acc_2 += w2*x, cc = 0..255.
//   u = x - acc_s - b ; v = acc_2 ; e=|u[j]-v[i]| ; thresholded weighted sum.
// -----------------------------------------------------------------------------
__global__ __launch_bounds__(256, 2) void fused_all(
    const float* __restrict__ x, const float* __restrict__ w,
    const float* __restrict__ bias, float* __restrict__ out)
{
    const int t  = threadIdx.x;
    const int tp = t & 15;   // p-frag: cols p0 + tp*2 .. +1
    const int td = t >> 4;   // d-frag: rows d0 + td*4 .. +3
    const int p0 = blockIdx.x * BP;
    const int d0 = blockIdx.y * BD;

    __shared__ float xs [2][NIMG][BK][BP];  // 2 x 10 KB
    __shared__ float w1s[2][BK][BD];        // 2 x 4 KB
    __shared__ float w2s[2][BK][BD];        // 2 x 4 KB

    float acc_s[NIMG][4][2] = {};  // sum_c x*(W1+W2)
    float acc_2[NIMG][4][2] = {};  // sum_c x*W2

    const int wv = t >> 6, l = t & 63;
    // x chunk (1KB = 8 rows x 32 floats): lane l -> row l>>3, col (l&7)*4
    const int xr = l >> 3, xc = (l & 7) * 4;
    // w chunk (1KB = 4 rows x 64 floats): lane l -> row l>>4, col (l&15)*4
    const int wr = l >> 4, wc = (l & 15) * 4;

    // Stage one K-step into buffer b. Wave roles (uniform dest per gload16):
    //  wv 0,1: 5 x-chunks each (10 total: (n,half) pairs)
    //  wv 2  : 4 w1-chunks ;  wv 3: 4 w2-chunks
    auto stage = [&](int b, int c0) {
        if (wv < 2) {
            #pragma unroll
            for (int s = 0; s < 5; ++s) {
                const int g = wv * 5 + s;
                const int n = g >> 1, half = g & 1;
                gload16(&x[(size_t)n * PT + (size_t)(c0 + half * 8 + xr) * HWP + p0 + xc],
                        &xs[b][n][half * 8][0]);
            }
        } else if (wv == 2) {
            #pragma unroll
            for (int k = 0; k < 4; ++k)
                gload16(&w[(size_t)(c0 + k * 4 + wr) * CCH + d0 + wc],
                        &w1s[b][k * 4][0]);
        } else {
            #pragma unroll
            for (int k = 0; k < 4; ++k)
                gload16(&w[(size_t)(256 + c0 + k * 4 + wr) * CCH + d0 + wc],
                        &w2s[b][k * 4][0]);
        }
    };

    stage(0, 0);

    for (int st = 0; st < NSTEP; ++st) {
        const int cur = st & 1;
        if (st + 1 < NSTEP) {
            stage(cur ^ 1, (st + 1) * BK);
            // wait for THIS wave's step-st loads (next step's stay in flight)
            if (wv < 2) asm volatile("s_waitcnt vmcnt(5)" ::: "memory");
            else        asm volatile("s_waitcnt vmcnt(4)" ::: "memory");
        } else {
            asm volatile("s_waitcnt vmcnt(0)" ::: "memory");
        }
        __builtin_amdgcn_s_barrier();   // buffer cur fully staged (all waves)

        #pragma unroll
        for (int cc = 0; cc < BK; ++cc) {
            const float4 w1v = *reinterpret_cast<const float4*>(&w1s[cur][cc][td * 4]);
            const float4 w2v = *reinterpret_cast<const float4*>(&w2s[cur][cc][td * 4]);
            const float w2a[4] = {w2v.x, w2v.y, w2v.z, w2v.w};
            const float wsa[4] = {w1v.x + w2v.x, w1v.y + w2v.y,
                                  w1v.z + w2v.z, w1v.w + w2v.w};
            #pragma unroll
            for (int n = 0; n < NIMG; ++n) {
                const float2 xv = *reinterpret_cast<const float2*>(&xs[cur][n][cc][tp * 2]);
                const float xa[2] = {xv.x, xv.y};
                #pragma unroll
                for (int i = 0; i < 4; ++i) {
                    #pragma unroll
                    for (int j = 0; j < 2; ++j) {
                        acc_s[n][i][j] = fmaf(wsa[i], xa[j], acc_s[n][i][j]);
                        acc_2[n][i][j] = fmaf(w2a[i], xa[j], acc_2[n][i][j]);
                    }
                }
            }
        }
        __builtin_amdgcn_s_barrier();   // compute done before re-staging cur^1
    }

    // ---------------- fused epilogue: edges + threshold + reduce ----------------
    #pragma unroll
    for (int r = 0; r < 4; ++r) {
        const int d = d0 + td * 4 + r;
        const float bd = bias[d];
        const size_t base = (size_t)d * HWP + p0 + tp * 2;

        float xa[NIMG][2], ua[NIMG][2], va[NIMG][2];
        #pragma unroll
        for (int n = 0; n < NIMG; ++n) {
            const float2 xv = *reinterpret_cast<const float2*>(&x[(size_t)n * PT + base]);
            const float xt[2] = {xv.x, xv.y};
            #pragma unroll
            for (int q = 0; q < 2; ++q) {
                xa[n][q] = xt[q];
                ua[n][q] = xt[q] - acc_s[n][r][q] - bd;
                va[n][q] = acc_2[n][r][q];
            }
        }

        #pragma unroll
        for (int i = 0; i < NIMG; ++i) {
            float ho[2];
            #pragma unroll
            for (int q = 0; q < 2; ++q) {
                float e[NIMG];
                float sumsq = 0.0f;
                #pragma unroll
                for (int j = 0; j < NIMG; ++j) {
                    e[j] = fabsf(ua[j][q] - va[i][q]);
                    sumsq = fmaf(e[j], e[j], sumsq);
                }
                const float m = fmaxf(sqrtf(sumsq), 1e-12f);
                float h = 0.0f;
                #pragma unroll
                for (int j = 0; j < NIMG; ++j) {
                    const float en = e[j] / m;
                    if (en > 0.35f) h = fmaf(e[j], xa[j][q], h);
                }
                ho[q] = h;
            }
            const float2 ov = {ho[0], ho[1]};
            *reinterpret_cast<float2*>(&out[(size_t)i * PT + base]) = ov;
        }
    }
}

extern "C" void kernel_launch(void* const* d_in, const int* in_sizes, int n_in,
                              void* d_out, int out_size, void* d_ws, size_t ws_size,
                              hipStream_t stream) {
    const float* x    = (const float*)d_in[0];
    const float* w    = (const float*)d_in[1];
    const float* bias = (const float*)d_in[2];
    float* out = (float*)d_out;

    dim3 g(HWP / BP, CCH / BD);   // 128 x 4 = 512 blocks, 2 per CU
    fused_all<<<g, 256, 0, stream>>>(x, w, bias, out);
}